// Round 2
// baseline (460.889 us; speedup 1.0000x reference)
//
#include <hip/hip_runtime.h>

#define NROW 16384
#define DDIM 128

typedef _Float16 f16x8 __attribute__((ext_vector_type(8)));
typedef float f32x4 __attribute__((ext_vector_type(4)));

__device__ __forceinline__ unsigned short f2h(float x) {
  union { _Float16 f; unsigned short u; } cvt;
  cvt.f = (_Float16)x;  // v_cvt_f16_f32, RNE
  return cvt.u;
}

__device__ __forceinline__ void gll16(const void* g, void* l) {
  __builtin_amdgcn_global_load_lds(
      (const __attribute__((address_space(1))) unsigned int*)g,
      (__attribute__((address_space(3))) unsigned int*)l, 16, 0, 0);
}

// ---------------- prep: ht[d][i] = fp16(h[i][d]) ----------------
__global__ __launch_bounds__(256) void prep_ht(const float* __restrict__ h,
                                               unsigned short* __restrict__ ht) {
  __shared__ unsigned short tile[DDIM][65];
  const int t = threadIdx.x;
  const int i0 = blockIdx.x * 64;
#pragma unroll
  for (int rep = 0; rep < 8; ++rep) {
    int idx = rep * 256 + t;
    int r = idx >> 5, c4 = idx & 31;
    const float4 v = *(const float4*)(h + (size_t)(i0 + r) * DDIM + c4 * 4);
    int c = c4 * 4;
    tile[c + 0][r] = f2h(v.x);
    tile[c + 1][r] = f2h(v.y);
    tile[c + 2][r] = f2h(v.z);
    tile[c + 3][r] = f2h(v.w);
  }
  __syncthreads();
#pragma unroll
  for (int rep = 0; rep < 4; ++rep) {
    int idx = rep * 256 + t;
    int d = idx >> 3, io = (idx & 7) * 8;
    uint4 o;
    o.x = (unsigned)tile[d][io + 0] | ((unsigned)tile[d][io + 1] << 16);
    o.y = (unsigned)tile[d][io + 2] | ((unsigned)tile[d][io + 3] << 16);
    o.z = (unsigned)tile[d][io + 4] | ((unsigned)tile[d][io + 5] << 16);
    o.w = (unsigned)tile[d][io + 6] | ((unsigned)tile[d][io + 7] << 16);
    *(uint4*)(ht + (size_t)d * NROW + i0 + io) = o;
  }
}

// ---------------- fused: out = rownorm(exp(adj)) @ h ----------------
// One wave per block (64 threads). BM=32 rows, wave tile 32x128, BK=64.
// A: global->register direct (no LDS), exp in-register, rowsum fused.
// B: global_load_lds DMA, double-buffered 2x16KB, XOR-swizzled via source.
// No barriers; counted s_waitcnt vmcnt(24) keeps 24 next-tile ops in flight.
__global__ __launch_bounds__(64, 1) void fused(const float* __restrict__ adj,
                                               const unsigned short* __restrict__ ht,
                                               float* __restrict__ out) {
  __shared__ __align__(16) char bsm[32768];  // B: 2 x [128 d][64 k] fp16
  const int l = threadIdx.x;                 // 0..63
  const int lr = l & 15, kg = l >> 4;
  const size_t m0 = (size_t)blockIdx.x * 32;

  // A direct-load base: lane covers adj[m0 + rg*16 + lr][half*32 + kg*8 + q*4 ..]
  const float* abase = adj + (m0 + lr) * (size_t)NROW + kg * 8;

  // DMA source: inst j covers d = j*8 + dd; slot = l&7; semantic chunk kc = slot^dd
  const int dd = l >> 3;
  const int kc = (l & 7) ^ dd;
  const unsigned short* hbase = ht + (size_t)dd * NROW + kc * 8;

  // B read byte-offsets (cg adds 2048): [d=cg*16+lr][k-chunk half*4+kg], swizzled
  const int r7 = lr & 7;
  const int boff0 = lr * 128 + ((kg ^ r7) << 4);        // half 0
  const int boff1 = lr * 128 + (((4 + kg) ^ r7) << 4);  // half 1

  f32x4 acc[2][8];
#pragma unroll
  for (int rg = 0; rg < 2; ++rg)
#pragma unroll
    for (int cg = 0; cg < 8; ++cg) acc[rg][cg] = (f32x4){0.f, 0.f, 0.f, 0.f};
  float rs0 = 0.f, rs1 = 0.f;

  // prologue: issue A[0] (8 loads) then DMA[0] (16 loads) into buf0
  float4 pa[8];
#pragma unroll
  for (int i = 0; i < 8; ++i) {
    const int rg = i >> 2, hf = (i >> 1) & 1, q = i & 1;
    pa[i] = *(const float4*)(abase + rg * 16 * NROW + hf * 32 + q * 4);
  }
#pragma unroll
  for (int j = 0; j < 16; ++j)
    gll16(hbase + j * 8 * NROW, bsm + j * 1024);

  for (int t = 0; t < NROW / 64; ++t) {
    const int cur = t & 1;
    const int nk0 = ((t + 1) & 255) * 64;  // last iter: redundant tile-0 (harmless)

    float4 a[8];
#pragma unroll
    for (int i = 0; i < 8; ++i) a[i] = pa[i];

    // issue A[t+1] (8) then DMA[t+1] (16) into the other buffer
#pragma unroll
    for (int i = 0; i < 8; ++i) {
      const int rg = i >> 2, hf = (i >> 1) & 1, q = i & 1;
      pa[i] = *(const float4*)(abase + rg * 16 * NROW + nk0 + hf * 32 + q * 4);
    }
    char* dstb = bsm + (cur ^ 1) * 16384;
#pragma unroll
    for (int j = 0; j < 16; ++j)
      gll16(hbase + nk0 + j * 8 * NROW, dstb + j * 1024);

    // retire iter t's 24 oldest (A[t] + DMA[t]); keep t+1's 24 in flight
    asm volatile("s_waitcnt vmcnt(24)" ::: "memory");
    __builtin_amdgcn_sched_barrier(0);

    // exp + f16 fragments + rowsum (all in-register)
    f16x8 af[2][2];
#pragma unroll
    for (int rg = 0; rg < 2; ++rg) {
#pragma unroll
      for (int hf = 0; hf < 2; ++hf) {
        const float4 x0 = a[rg * 4 + hf * 2 + 0];
        const float4 x1 = a[rg * 4 + hf * 2 + 1];
        const float e0 = __expf(x0.x), e1 = __expf(x0.y);
        const float e2 = __expf(x0.z), e3 = __expf(x0.w);
        const float e4 = __expf(x1.x), e5 = __expf(x1.y);
        const float e6 = __expf(x1.z), e7 = __expf(x1.w);
        f16x8 v;
        v[0] = (_Float16)e0; v[1] = (_Float16)e1;
        v[2] = (_Float16)e2; v[3] = (_Float16)e3;
        v[4] = (_Float16)e4; v[5] = (_Float16)e5;
        v[6] = (_Float16)e6; v[7] = (_Float16)e7;
        af[rg][hf] = v;
        const float s = ((e0 + e1) + (e2 + e3)) + ((e4 + e5) + (e6 + e7));
        if (rg == 0) rs0 += s; else rs1 += s;
      }
    }

    const char* bB = bsm + cur * 16384;
#pragma unroll
    for (int cg = 0; cg < 8; ++cg) {
      const f16x8 b0 = *(const f16x8*)(bB + boff0 + cg * 2048);
      acc[0][cg] = __builtin_amdgcn_mfma_f32_16x16x32_f16(af[0][0], b0, acc[0][cg], 0, 0, 0);
      acc[1][cg] = __builtin_amdgcn_mfma_f32_16x16x32_f16(af[1][0], b0, acc[1][cg], 0, 0, 0);
      const f16x8 b1 = *(const f16x8*)(bB + boff1 + cg * 2048);
      acc[0][cg] = __builtin_amdgcn_mfma_f32_16x16x32_f16(af[0][1], b1, acc[0][cg], 0, 0, 0);
      acc[1][cg] = __builtin_amdgcn_mfma_f32_16x16x32_f16(af[1][1], b1, acc[1][cg], 0, 0, 0);
    }
  }

  // rowsum reduce across the 4 kg-lanes holding each row (lanes l, l^16, l^32, l^48)
  rs0 += __shfl_xor(rs0, 16); rs0 += __shfl_xor(rs0, 32);
  rs1 += __shfl_xor(rs1, 16); rs1 += __shfl_xor(rs1, 32);

  // epilogue: D row = kg*4 + r (within 16-row group), col = cg*16 + lr
#pragma unroll
  for (int r = 0; r < 4; ++r) {
    const int src = kg * 4 + r;  // lane holding that row's sum (lr == src)
    const float inv0 = 1.0f / __shfl(rs0, src);
    const float inv1 = 1.0f / __shfl(rs1, src);
    float* o0 = out + (m0 + src) * (size_t)DDIM + lr;
    float* o1 = out + (m0 + 16 + src) * (size_t)DDIM + lr;
#pragma unroll
    for (int cg = 0; cg < 8; ++cg) {
      o0[cg * 16] = acc[0][cg][r] * inv0;
      o1[cg * 16] = acc[1][cg][r] * inv1;
    }
  }
}

extern "C" void kernel_launch(void* const* d_in, const int* in_sizes, int n_in,
                              void* d_out, int out_size, void* d_ws, size_t ws_size,
                              hipStream_t stream) {
  (void)in_sizes; (void)n_in; (void)out_size; (void)ws_size;
  const float* h   = (const float*)d_in[0];
  const float* adj = (const float*)d_in[1];
  float* out = (float*)d_out;
  unsigned short* ht = (unsigned short*)d_ws;  // 128*16384 fp16 = 4 MB

  prep_ht<<<dim3(NROW / 64), dim3(256), 0, stream>>>(h, ht);
  fused<<<dim3(NROW / 32), dim3(64), 0, stream>>>(adj, ht, out);
}